// Round 3
// 2814.430 us; speedup vs baseline: 1.9499x; 1.9499x over previous
//
#include <hip/hip_runtime.h>
#include <cmath>

// One workgroup (512 threads) per sample.
// VERBATIM the original passing kernel (absmax 4096), with exactly two
// provably bit-identical structural changes:
//   1. theta-gate early exit after the forward pass (gated samples' outputs
//      are identical to what the original kernel wrote for them).
//   2. h0f/h1f aliased into tmpf (LDS 33.8KB -> 29.3KB for 2 blocks/CU);
//      same values, different storage, uses separated by existing barriers.
__global__ __launch_bounds__(512, 1)
void leql_f32_kernel(const float* __restrict__ x,
                     const float* __restrict__ W0g, const float* __restrict__ b0g,
                     const float* __restrict__ W1g, const float* __restrict__ b1g,
                     const float* __restrict__ Wog, const float* __restrict__ bog,
                     float* __restrict__ out, int B)
{
    __shared__ float uf[32];
    __shared__ float WoS[1024];
    __shared__ float z0f[512], z1f[512];
    __shared__ float s0f[256], c0f[256], s1f[256], c1f[256];
    __shared__ float h1df[512];
    __shared__ float whatf[384];
    __shared__ float v0f[384];
    __shared__ float tmpf[512];          // also holds h0, then h1 (aliased)
    __shared__ float hd0f[384];
    __shared__ float zd1f[512];
    __shared__ float vd0f[384];
    __shared__ float Hf[32][17];
    __shared__ float yvf[2], ydf[2];
    __shared__ float Af[16][33], rf[16], qdo[16];
    __shared__ float wkc[16];
    __shared__ int ipiv[16];
    __shared__ int pivS;

    const int t = threadIdx.x;
    const int s = blockIdx.x;

    if (t < 32) uf[t] = x[s*32 + t];
    WoS[t] = Wog[t]; WoS[512+t] = Wog[512+t];
    __syncthreads();

    // ---- forward ----
    {
        const float* wr = &W0g[(128+t)*32];
        float acc = 0.0f;
        for (int c = 0; c < 32; ++c) acc = fmaf(wr[c], uf[c], acc);
        z0f[t] = __fadd_rn(acc, b0g[128+t]);
    }
    __syncthreads();
    if (t < 256) { s0f[t] = sinf(z0f[t]); c0f[t] = cosf(z0f[t]); }
    __syncthreads();
    if (t < 128)      tmpf[t] = 1.0f;                          // h0
    else if (t < 256) tmpf[t] = s0f[t-128];
    else if (t < 384) tmpf[t] = c0f[t-128];
    else              tmpf[t] = __fmul_rn(z0f[t-128], z0f[t]);
    __syncthreads();
    {
        const float* wr = &W1g[(size_t)(128+t)*512];
        float acc = 0.0f;
        for (int m = 0; m < 512; ++m) acc = fmaf(wr[m], tmpf[m], acc);
        z1f[t] = __fadd_rn(acc, b1g[128+t]);
    }
    __syncthreads();
    if (t < 256) { s1f[t] = sinf(z1f[t]); c1f[t] = cosf(z1f[t]); }
    __syncthreads();
    if (t < 128)      tmpf[t] = 1.0f;                          // h1
    else if (t < 256) tmpf[t] = s1f[t-128];
    else if (t < 384) tmpf[t] = c1f[t-128];
    else              tmpf[t] = __fmul_rn(z1f[t-128], z1f[t]);
    __syncthreads();
    if (t < 2) {
        float acc = 0.0f;
        for (int n = 0; n < 512; ++n) acc = fmaf(WoS[t*512 + n], tmpf[n], acc);
        yvf[t] = __fadd_rn(acc, bog[t]);
    }
    __syncthreads();

    // ---- quotient-rule seeds, jax-lax form ----
    const float y1 = yvf[0], y2 = yvf[1];

    // theta-gate early exit: for y2 <= 0.5 the reference where() zeroes the
    // cotangent exactly (jcob = h1 = h2 = 0), so qdd = inv(eps I) @ 0 = 0 and
    // lg = 0 -- identical to what the original kernel wrote for these samples.
    if (!(y2 > 0.5f)) {
        if (t < 16)  out[s*16 + t] = 0.0f;
        if (t == 16) out[(size_t)B*16 + s] = 0.0f;
        if (t == 17) out[(size_t)B*17 + s] = y2;
        return;
    }

    const float y2sq = __fmul_rn(y2, y2);
    const float r2 = 1.0f / y2sq;                       // integer_pow(y2,-2)
    const float r3 = 1.0f / __fmul_rn(y2sq, y2);        // integer_pow(y2,-3)
    const float sd1f = 1.0f / y2;                       // div VJP wrt numerator
    const float sd2f = __fmul_rn(-y1, r2);              // mul(mul(neg(ct),y1),y2^-2)

    // ---- base reverse pass ----
    if (t < 384) {                                       // Wo^T @ seed: fmaf k-chain
        float acc = fmaf(WoS[128+t], sd1f, 0.0f);
        whatf[t] = fmaf(WoS[512+128+t], sd2f, acc);
    }
    __syncthreads();
    {
        float v;
        if (t < 128)      v =  __fmul_rn(whatf[t],     c1f[t]);
        else if (t < 256) v = -__fmul_rn(whatf[t],     s1f[t]);
        else if (t < 384) v =  __fmul_rn(whatf[t],     z1f[t+128]);
        else              v =  __fmul_rn(whatf[t-128], z1f[t-128]);
        tmpf[t] = v;
    }
    __syncthreads();
    if (t < 384) {
        const float* wc = &W1g[(size_t)128*512 + 128 + t];
        float acc = 0.0f;
        for (int p = 0; p < 512; ++p) acc = fmaf(tmpf[p], wc[(size_t)p*512], acc);
        v0f[t] = acc;
    }
    __syncthreads();
    {
        float v;
        if (t < 128)      v =  __fmul_rn(v0f[t],     c0f[t]);
        else if (t < 256) v = -__fmul_rn(v0f[t],     s0f[t]);
        else if (t < 384) v =  __fmul_rn(v0f[t],     z0f[t+128]);
        else              v =  __fmul_rn(v0f[t-128], z0f[t-128]);
        tmpf[t] = v;
    }
    __syncthreads();
    if (t < 32) {
        float acc = 0.0f;
        for (int p = 0; p < 512; ++p) acc = fmaf(tmpf[p], W0g[(128+p)*32 + t], acc);
        Hf[t][16] = acc;
    }
    __syncthreads();

    // ---- 16 tangent passes ----
    for (int j = 0; j < 16; ++j) {
        const int cj = 16 + j;
        if (t < 384) {
            float v;
            if (t < 128)      v =  __fmul_rn(c0f[t], W0g[(128+t)*32 + cj]);
            else if (t < 256) v = -__fmul_rn(s0f[t], W0g[(128+t)*32 + cj]);
            else {
                int i = t - 256;
                v = __fadd_rn(__fmul_rn(W0g[(384+i)*32 + cj], z0f[384+i]),
                              __fmul_rn(z0f[256+i], W0g[(512+i)*32 + cj]));
            }
            hd0f[t] = v;
        }
        __syncthreads();
        {
            const float* wr = &W1g[(size_t)(128+t)*512 + 128];
            float acc = 0.0f;
            for (int m = 0; m < 384; ++m) acc = fmaf(wr[m], hd0f[m], acc);
            zd1f[t] = acc;
        }
        __syncthreads();
        {
            float v;
            if (t < 128)      v = 0.0f;
            else if (t < 256) v =  __fmul_rn(c1f[t-128], zd1f[t-128]);
            else if (t < 384) v = -__fmul_rn(s1f[t-128], zd1f[t-128]);
            else              v = __fadd_rn(__fmul_rn(zd1f[t-128], z1f[t]),
                                            __fmul_rn(z1f[t-128], zd1f[t]));
            h1df[t] = v;
        }
        __syncthreads();
        if (t < 2) {
            float acc = 0.0f;
            for (int n = 0; n < 512; ++n) acc = fmaf(WoS[t*512 + n], h1df[n], acc);
            ydf[t] = acc;
        }
        __syncthreads();
        {   // vdot1, jax-JVP associations
            float yd1 = ydf[0], yd2 = ydf[1];
            float sdot1 = __fmul_rn(-yd2, r2);
            float dr2 = __fmul_rn(__fmul_rn(yd2, -2.0f), r3);
            float sdot2 = __fadd_rn(__fmul_rn(-yd1, r2), __fmul_rn(-y1, dr2));
            int n = (t < 384) ? (128 + t) : t;
            float wd = fmaf(WoS[512+n], sdot2, fmaf(WoS[n], sdot1, 0.0f));
            float v;
            if (t < 128) {                       // sin node: what*cos(z1)
                float dcs = __fmul_rn(zd1f[t], -s1f[t]);      // d(cos) = zd*(-sin)
                v = __fadd_rn(__fmul_rn(wd, c1f[t]), __fmul_rn(whatf[t], dcs));
            } else if (t < 256) {                // cos node: what*(-sin(z1))
                float dsn = __fmul_rn(zd1f[t], c1f[t]);       // d(sin) = zd*cos
                v = __fadd_rn(__fmul_rn(wd, -s1f[t]), __fmul_rn(whatf[t], -dsn));
            } else if (t < 384) {
                v = __fadd_rn(__fmul_rn(wd, z1f[t+128]),
                              __fmul_rn(whatf[t], zd1f[t+128]));
            } else {
                v = __fadd_rn(__fmul_rn(wd, z1f[t-128]),
                              __fmul_rn(whatf[t-128], zd1f[t-128]));
            }
            tmpf[t] = v;
        }
        __syncthreads();
        if (t < 384) {
            const float* wc = &W1g[(size_t)128*512 + 128 + t];
            float acc = 0.0f;
            for (int p = 0; p < 512; ++p) acc = fmaf(tmpf[p], wc[(size_t)p*512], acc);
            vd0f[t] = acc;
        }
        __syncthreads();
        {   // dzdot0, jax-JVP associations
            float v;
            if (t < 128) {                       // sin z0 node: v0*cos(z0)
                float e = W0g[(128+t)*32 + cj];
                float dcs = __fmul_rn(e, -s0f[t]);
                v = __fadd_rn(__fmul_rn(vd0f[t], c0f[t]), __fmul_rn(v0f[t], dcs));
            } else if (t < 256) {                // cos z0 node: v0*(-sin(z0))
                float e = W0g[(128+t)*32 + cj];
                float dsn = __fmul_rn(e, c0f[t]);
                v = __fadd_rn(__fmul_rn(vd0f[t], -s0f[t]), __fmul_rn(v0f[t], -dsn));
            } else if (t < 384) {
                float eb = W0g[(256+t)*32 + cj];
                v = __fadd_rn(__fmul_rn(vd0f[t], z0f[t+128]), __fmul_rn(v0f[t], eb));
            } else {
                float ea = W0g[t*32 + cj];
                v = __fadd_rn(__fmul_rn(vd0f[t-128], z0f[t-128]), __fmul_rn(v0f[t-128], ea));
            }
            tmpf[t] = v;
        }
        __syncthreads();
        if (t < 32) {
            float acc = 0.0f;
            for (int p = 0; p < 512; ++p) acc = fmaf(tmpf[p], W0g[(128+p)*32 + t], acc);
            Hf[t][j] = acc;
        }
        __syncthreads();
    }

    // ---- A = h1 + eps I; rhs = jcob - h2@q ----
    if (t < 256) {
        int i = t >> 4, jj = t & 15;
        Af[i][jj] = (i == jj) ? __fadd_rn(Hf[16+i][jj], 1.0e-3f) : Hf[16+i][jj];
    }
    if (t >= 256 && t < 272) {
        int i = t - 256;
        float dd = 0.0f;
        for (int jj = 0; jj < 16; ++jj) dd = fmaf(Hf[i][jj], uf[jj], dd);
        rf[i] = __fsub_rn(Hf[i][16], dd);
    }
    __syncthreads();

    // sgetf2
    for (int j = 0; j < 16; ++j) {
        if (t == 0) {
            int p = j; float best = fabsf(Af[j][j]);
            for (int r = j+1; r < 16; ++r) {
                float v = fabsf(Af[r][j]);
                if (v > best) { best = v; p = r; }
            }
            ipiv[j] = p; pivS = p;
        }
        __syncthreads();
        int piv = pivS;
        if (piv != j && t < 16) {
            float tv = Af[j][t]; Af[j][t] = Af[piv][t]; Af[piv][t] = tv;
        }
        __syncthreads();
        float recip = 1.0f / Af[j][j];
        if (t > j && t < 16) Af[t][j] = __fmul_rn(Af[t][j], recip);
        __syncthreads();
        if (t < 256) {
            int i = t >> 4, k = t & 15;
            if (i > j && k > j) Af[i][k] = fmaf(-Af[i][j], Af[j][k], Af[i][k]);
        }
        __syncthreads();
    }

    // sgetri: strti2 + descending-j sweep + reverse column pivots
    if (t == 0) {
        for (int j = 0; j < 16; ++j) {
            float ajj_inv = 1.0f / Af[j][j];
            Af[j][j] = ajj_inv;
            float ajj = -ajj_inv;
            for (int j2 = 0; j2 < j; ++j2) {
                float temp = Af[j2][j];
                if (temp != 0.0f)
                    for (int i = 0; i < j2; ++i)
                        Af[i][j] = fmaf(temp, Af[i][j2], Af[i][j]);
                Af[j2][j] = __fmul_rn(Af[j2][j], Af[j2][j2]);
            }
            for (int i = 0; i < j; ++i) Af[i][j] = __fmul_rn(Af[i][j], ajj);
        }
    }
    __syncthreads();
    for (int j = 15; j >= 0; --j) {
        if (t > j && t < 16) { wkc[t] = Af[t][j]; Af[t][j] = 0.0f; }
        __syncthreads();
        if (t < 16) {
            float acc = Af[t][j];
            for (int k = j+1; k < 16; ++k) acc = fmaf(-wkc[k], Af[t][k], acc);
            Af[t][j] = acc;
        }
        __syncthreads();
    }
    if (t < 16) {
        for (int j = 15; j >= 0; --j) {
            int jp = ipiv[j];
            if (jp != j) { float tv = Af[t][j]; Af[t][j] = Af[t][jp]; Af[t][jp] = tv; }
        }
    }
    __syncthreads();

    // qdd = inv @ rhs
    if (t < 16) {
        float acc = 0.0f;
        for (int jj = 0; jj < 16; ++jj) acc = fmaf(Af[t][jj], rf[jj], acc);
        qdo[t] = acc;
    }
    __syncthreads();

    // ---- outputs (gate is true on this path) ----
    if (t < 16)  out[s*16 + t] = qdo[t];
    if (t == 16) out[(size_t)B*16 + s] = y1 / y2;
    if (t == 17) out[(size_t)B*17 + s] = y2;
}

extern "C" void kernel_launch(void* const* d_in, const int* in_sizes, int n_in,
                              void* d_out, int out_size, void* d_ws, size_t ws_size,
                              hipStream_t stream) {
    (void)n_in; (void)out_size; (void)d_ws; (void)ws_size;
    const float* x  = (const float*)d_in[0];
    const float* W0 = (const float*)d_in[1];
    const float* b0 = (const float*)d_in[2];
    const float* W1 = (const float*)d_in[3];
    const float* b1 = (const float*)d_in[4];
    const float* Wo = (const float*)d_in[5];
    const float* bo = (const float*)d_in[6];
    const int B = in_sizes[0] / 32;
    hipLaunchKernelGGL(leql_f32_kernel, dim3(B), dim3(512), 0, stream,
                       x, W0, b0, W1, b1, Wo, bo, (float*)d_out, B);
}